// Round 1
// baseline (713.192 us; speedup 1.0000x reference)
//
#include <hip/hip_runtime.h>
#include <hip/hip_bf16.h>
#include <math.h>

// ---------------- CSR build ----------------

__global__ void k_count(const int* __restrict__ dst, int* __restrict__ cnt, int E) {
    int e = blockIdx.x * 256 + threadIdx.x;
    if (e < E) atomicAdd(&cnt[dst[e]], 1);
}

__global__ void k_dinv(const int* __restrict__ cnt, float* __restrict__ dinv, int n) {
    int i = blockIdx.x * 256 + threadIdx.x;
    if (i < n) dinv[i] = 1.0f / sqrtf((float)cnt[i] + 1.0f);  // +1 self-loop
}

__global__ void k_scan_part(const int* __restrict__ cnt, int* __restrict__ offs,
                            int* __restrict__ parts, int n) {
    __shared__ int s[256];
    int i = blockIdx.x * 256 + threadIdx.x;
    int v = (i < n) ? cnt[i] : 0;
    s[threadIdx.x] = v;
    __syncthreads();
    #pragma unroll
    for (int d = 1; d < 256; d <<= 1) {
        int t = (threadIdx.x >= d) ? s[threadIdx.x - d] : 0;
        __syncthreads();
        s[threadIdx.x] += t;
        __syncthreads();
    }
    if (i < n) offs[i] = s[threadIdx.x] - v;        // block-local exclusive
    if (threadIdx.x == 255) parts[blockIdx.x] = s[255];
}

__global__ void k_scan_tops(int* __restrict__ parts, int np) {
    __shared__ int s[256];
    int tid = threadIdx.x;
    int v = (tid < np) ? parts[tid] : 0;
    s[tid] = v;
    __syncthreads();
    #pragma unroll
    for (int d = 1; d < 256; d <<= 1) {
        int t = (tid >= d) ? s[tid - d] : 0;
        __syncthreads();
        s[tid] += t;
        __syncthreads();
    }
    if (tid < np) parts[tid] = s[tid] - v;          // exclusive
}

__global__ void k_scan_add(int* __restrict__ offs, const int* __restrict__ parts,
                           int n, int e_total) {
    int i = blockIdx.x * 256 + threadIdx.x;
    if (i < n) offs[i] += parts[blockIdx.x];
    if (blockIdx.x == 0 && threadIdx.x == 0) offs[n] = e_total;
}

__global__ void k_scatter(const int* __restrict__ dst, const int* __restrict__ src,
                          const int* __restrict__ offs, int* __restrict__ cur,
                          int* __restrict__ csr, int E) {
    int e = blockIdx.x * 256 + threadIdx.x;
    if (e < E) {
        int d = dst[e];
        int pos = offs[d] + atomicAdd(&cur[d], 1);
        csr[pos] = src[e];
    }
}

// ---------------- SpMM: support = 0.9*A_hat*h + 0.1*h0 ----------------
// one wave per destination node, each lane owns a float2 of the 128 features

__global__ __launch_bounds__(256)
void k_spmm(const int* __restrict__ offs, const int* __restrict__ csr,
            const float* __restrict__ dinv, const float* __restrict__ h,
            const float* __restrict__ h0, float* __restrict__ sup, int n) {
    int node = (blockIdx.x << 2) + (threadIdx.x >> 6);
    if (node >= n) return;
    int lane = threadIdx.x & 63;
    const float2* h2  = (const float2*)h;
    const float2* h02 = (const float2*)h0;
    float di = dinv[node];
    float2 v  = h2[(size_t)node * 64 + lane];
    float2 a0 = h02[(size_t)node * 64 + lane];
    float w0 = 0.9f * di * di;
    float ax = w0 * v.x + 0.1f * a0.x;
    float ay = w0 * v.y + 0.1f * a0.y;
    float dn = 0.9f * di;
    int e = offs[node], end = offs[node + 1];
    for (; e < end; ++e) {
        int s = csr[e];
        float w = dn * dinv[s];
        float2 hv = h2[(size_t)s * 64 + lane];
        ax += w * hv.x;
        ay += w * hv.y;
    }
    float2 o; o.x = ax; o.y = ay;
    ((float2*)sup)[(size_t)node * 64 + lane] = o;
}

// ---------------- 128x128 fp32 GEMM, fused residual+relu ----------------
// out[r][c] = relu( beta*(in@W)[r][c] + resid*in[r][c] + bias[c] )

template<bool RELU, bool DUAL>
__global__ __launch_bounds__(256)
void gemm128(const float* __restrict__ in, const float* __restrict__ W,
             const float* __restrict__ bias, float beta, float resid,
             float* __restrict__ out, float* __restrict__ out2, int M) {
    __shared__ float Ws[32 * 128];   // K-panel of W
    __shared__ float xT[128 * 32];   // x tile, transposed [k][r]
    const int tid  = threadIdx.x;
    const int row0 = blockIdx.x * 32;

    // load x tile transposed
    {
        const float4* in4 = (const float4*)in;
        for (int i = tid; i < 1024; i += 256) {       // 32 rows x 32 float4
            int r = i >> 5, c4 = i & 31;
            int gr = row0 + r;
            float4 v = make_float4(0.f, 0.f, 0.f, 0.f);
            if (gr < M) v = in4[(size_t)gr * 32 + c4];
            xT[(c4 * 4 + 0) * 32 + r] = v.x;
            xT[(c4 * 4 + 1) * 32 + r] = v.y;
            xT[(c4 * 4 + 2) * 32 + r] = v.z;
            xT[(c4 * 4 + 3) * 32 + r] = v.w;
        }
    }
    const int tr = tid >> 5;   // 0..7  -> rows tr*4..tr*4+3
    const int tc = tid & 31;   // 0..31 -> cols tc*4..tc*4+3
    float acc[4][4];
    #pragma unroll
    for (int i = 0; i < 4; ++i)
        #pragma unroll
        for (int j = 0; j < 4; ++j) acc[i][j] = 0.f;

    for (int kp = 0; kp < 4; ++kp) {
        __syncthreads();
        const float4* Wp = (const float4*)(W + kp * 32 * 128);
        for (int i = tid; i < 1024; i += 256)          // 32x128 = 1024 float4
            ((float4*)Ws)[i] = Wp[i];
        __syncthreads();
        #pragma unroll 8
        for (int k2 = 0; k2 < 32; ++k2) {
            int k = kp * 32 + k2;
            float4 a = *(const float4*)&xT[k * 32 + tr * 4];
            float4 b = *(const float4*)&Ws[k2 * 128 + tc * 4];
            acc[0][0] += a.x * b.x; acc[0][1] += a.x * b.y; acc[0][2] += a.x * b.z; acc[0][3] += a.x * b.w;
            acc[1][0] += a.y * b.x; acc[1][1] += a.y * b.y; acc[1][2] += a.y * b.z; acc[1][3] += a.y * b.w;
            acc[2][0] += a.z * b.x; acc[2][1] += a.z * b.y; acc[2][2] += a.z * b.z; acc[2][3] += a.z * b.w;
            acc[3][0] += a.w * b.x; acc[3][1] += a.w * b.y; acc[3][2] += a.w * b.z; acc[3][3] += a.w * b.w;
        }
    }

    float bb[4] = {0.f, 0.f, 0.f, 0.f};
    if (bias) {
        #pragma unroll
        for (int j = 0; j < 4; ++j) bb[j] = bias[tc * 4 + j];
    }
    #pragma unroll
    for (int i = 0; i < 4; ++i) {
        int rl = tr * 4 + i;
        int r  = row0 + rl;
        if (r < M) {
            float4 o;
            float s0 = beta * acc[i][0] + resid * xT[(tc * 4 + 0) * 32 + rl] + bb[0];
            float s1 = beta * acc[i][1] + resid * xT[(tc * 4 + 1) * 32 + rl] + bb[1];
            float s2 = beta * acc[i][2] + resid * xT[(tc * 4 + 2) * 32 + rl] + bb[2];
            float s3 = beta * acc[i][3] + resid * xT[(tc * 4 + 3) * 32 + rl] + bb[3];
            if (RELU) {
                s0 = fmaxf(s0, 0.f); s1 = fmaxf(s1, 0.f);
                s2 = fmaxf(s2, 0.f); s3 = fmaxf(s3, 0.f);
            }
            o.x = s0; o.y = s1; o.z = s2; o.w = s3;
            *(float4*)&out[(size_t)r * 128 + tc * 4] = o;
            if (DUAL) *(float4*)&out2[(size_t)r * 128 + tc * 4] = o;
        }
    }
}

// ---------------- output GEMM: [M,128] @ [128,40] + b ----------------

__global__ __launch_bounds__(320)
void k_out(const float* __restrict__ h, const float* __restrict__ W,
           const float* __restrict__ b, float* __restrict__ out, int M, int C) {
    __shared__ float Ws[128 * 41];   // padded: bank-conflict-free scalar reads
    __shared__ float xs[32 * 132];   // padded rows, 16B-aligned float4 reads
    const int tid  = threadIdx.x;    // 320
    const int row0 = blockIdx.x * 32;

    for (int i = tid; i < 128 * 40; i += 320) {
        int k = i / 40, c = i % 40;
        Ws[k * 41 + c] = W[i];
    }
    {
        const float4* h4 = (const float4*)h;
        for (int i = tid; i < 1024; i += 320) {   // 32 rows x 32 float4
            int r = i >> 5, c4 = i & 31;
            int gr = row0 + r;
            float4 v = make_float4(0.f, 0.f, 0.f, 0.f);
            if (gr < M) v = h4[(size_t)gr * 32 + c4];
            *(float4*)&xs[r * 132 + c4 * 4] = v;
        }
    }
    __syncthreads();

    const int c  = tid % 40;
    const int rg = tid / 40;          // 0..7 -> rows rg*4..rg*4+3
    float acc[4] = {0.f, 0.f, 0.f, 0.f};
    #pragma unroll 4
    for (int k4 = 0; k4 < 32; ++k4) {
        float w0 = Ws[(k4 * 4 + 0) * 41 + c];
        float w1 = Ws[(k4 * 4 + 1) * 41 + c];
        float w2 = Ws[(k4 * 4 + 2) * 41 + c];
        float w3 = Ws[(k4 * 4 + 3) * 41 + c];
        #pragma unroll
        for (int i = 0; i < 4; ++i) {
            float4 x = *(const float4*)&xs[(rg * 4 + i) * 132 + k4 * 4];
            acc[i] += x.x * w0 + x.y * w1 + x.z * w2 + x.w * w3;
        }
    }
    float bb = b[c];
    #pragma unroll
    for (int i = 0; i < 4; ++i) {
        int r = row0 + rg * 4 + i;
        if (r < M) out[(size_t)r * C + c] = acc[i] + bb;
    }
}

// ---------------- host ----------------

extern "C" void kernel_launch(void* const* d_in, const int* in_sizes, int n_in,
                              void* d_out, int out_size, void* d_ws, size_t ws_size,
                              hipStream_t stream) {
    const float* x        = (const float*)d_in[0];
    const int*   ei       = (const int*)d_in[1];
    const float* W_in     = (const float*)d_in[2];
    const float* b_in     = (const float*)d_in[3];
    const float* W_layers = (const float*)d_in[4];
    const float* W_out    = (const float*)d_in[5];
    const float* b_out    = (const float*)d_in[6];
    float* out = (float*)d_out;

    const int H = 128;
    const int N = in_sizes[0] / H;             // 50000
    const int E = in_sizes[1] / 2;             // 800000
    const int L = in_sizes[4] / (H * H);       // 4
    const int C = in_sizes[5] / H;             // 40

    // workspace carve (256B aligned)
    char* p = (char*)d_ws;
    auto alloc = [&](size_t bytes) {
        char* r = p;
        p += (bytes + 255) & ~(size_t)255;
        return r;
    };
    int*   cnt   = (int*)alloc((size_t)N * 4);
    int*   offs  = (int*)alloc((size_t)(N + 1) * 4);
    int*   parts = (int*)alloc(256 * 4);
    int*   csr   = (int*)alloc((size_t)E * 4);
    float* dinv  = (float*)alloc((size_t)N * 4);
    float* h0    = (float*)alloc((size_t)N * H * 4);
    float* hA    = (float*)alloc((size_t)N * H * 4);
    float* hB    = (float*)alloc((size_t)N * H * 4);
    (void)ws_size;

    const int* ei0 = ei;        // destinations (row)
    const int* ei1 = ei + E;    // sources (col)

    const int nblkN = (N + 255) / 256;
    const int nblkE = (E + 255) / 256;

    hipMemsetAsync(cnt, 0, (size_t)N * 4, stream);
    k_count<<<nblkE, 256, 0, stream>>>(ei0, cnt, E);
    k_dinv<<<nblkN, 256, 0, stream>>>(cnt, dinv, N);
    k_scan_part<<<nblkN, 256, 0, stream>>>(cnt, offs, parts, N);
    k_scan_tops<<<1, 256, 0, stream>>>(parts, nblkN);
    k_scan_add<<<nblkN, 256, 0, stream>>>(offs, parts, N, E);
    hipMemsetAsync(cnt, 0, (size_t)N * 4, stream);
    k_scatter<<<nblkE, 256, 0, stream>>>(ei0, ei1, offs, cnt, csr, E);

    const int gblk = (N + 31) / 32;

    // input linear + relu -> hA, copy -> h0
    gemm128<true, true><<<gblk, 256, 0, stream>>>(x, W_in, b_in, 1.0f, 0.0f, hA, h0, N);

    for (int l = 0; l < L; ++l) {
        float beta = logf(0.5f / (float)(l + 1) + 1.0f);
        k_spmm<<<(N + 3) / 4, 256, 0, stream>>>(offs, csr, dinv, hA, h0, hB, N);
        gemm128<true, false><<<gblk, 256, 0, stream>>>(
            hB, W_layers + (size_t)l * H * H, nullptr, beta, 1.0f - beta, hA, nullptr, N);
    }

    k_out<<<gblk, 320, 0, stream>>>(hA, W_out, b_out, out, N, C);
}

// Round 2
// 589.718 us; speedup vs baseline: 1.2094x; 1.2094x over previous
//
#include <hip/hip_runtime.h>
#include <hip/hip_bf16.h>
#include <math.h>

// ---------------- CSR build ----------------

__global__ void k_count(const int* __restrict__ dst, int* __restrict__ cnt, int E) {
    int e = blockIdx.x * 256 + threadIdx.x;
    if (e < E) atomicAdd(&cnt[dst[e]], 1);
}

__global__ void k_dinv(const int* __restrict__ cnt, float* __restrict__ dinv, int n) {
    int i = blockIdx.x * 256 + threadIdx.x;
    if (i < n) dinv[i] = 1.0f / sqrtf((float)cnt[i] + 1.0f);  // +1 self-loop
}

__global__ void k_scan_part(const int* __restrict__ cnt, int* __restrict__ offs,
                            int* __restrict__ parts, int n) {
    __shared__ int s[256];
    int i = blockIdx.x * 256 + threadIdx.x;
    int v = (i < n) ? cnt[i] : 0;
    s[threadIdx.x] = v;
    __syncthreads();
    #pragma unroll
    for (int d = 1; d < 256; d <<= 1) {
        int t = (threadIdx.x >= d) ? s[threadIdx.x - d] : 0;
        __syncthreads();
        s[threadIdx.x] += t;
        __syncthreads();
    }
    if (i < n) offs[i] = s[threadIdx.x] - v;        // block-local exclusive
    if (threadIdx.x == 255) parts[blockIdx.x] = s[255];
}

__global__ void k_scan_tops(int* __restrict__ parts, int np) {
    __shared__ int s[256];
    int tid = threadIdx.x;
    int v = (tid < np) ? parts[tid] : 0;
    s[tid] = v;
    __syncthreads();
    #pragma unroll
    for (int d = 1; d < 256; d <<= 1) {
        int t = (tid >= d) ? s[tid - d] : 0;
        __syncthreads();
        s[tid] += t;
        __syncthreads();
    }
    if (tid < np) parts[tid] = s[tid] - v;          // exclusive
}

__global__ void k_scan_add(int* __restrict__ offs, const int* __restrict__ parts,
                           int n, int e_total) {
    int i = blockIdx.x * 256 + threadIdx.x;
    if (i < n) offs[i] += parts[blockIdx.x];
    if (blockIdx.x == 0 && threadIdx.x == 0) offs[n] = e_total;
}

// csr entry = {src, 0.9*dinv[dst]*dinv[src] as bits}
__global__ void k_scatter(const int* __restrict__ dst, const int* __restrict__ src,
                          const int* __restrict__ offs, int* __restrict__ cur,
                          const float* __restrict__ dinv, int2* __restrict__ csr, int E) {
    int e = blockIdx.x * 256 + threadIdx.x;
    if (e < E) {
        int d = dst[e], s = src[e];
        int pos = offs[d] + atomicAdd(&cur[d], 1);
        float w = 0.9f * dinv[d] * dinv[s];
        csr[pos] = make_int2(s, __float_as_int(w));
    }
}

// ---------------- SpMM: support = 0.9*A_hat*h + 0.1*h0 ----------------
// one wave per destination node, lane owns float2 of H; edge loop unrolled x4
// so 4 independent 512B gathers are in flight per wave.

__global__ __launch_bounds__(256)
void k_spmm(const int* __restrict__ offs, const int2* __restrict__ csr,
            const float* __restrict__ dinv, const float* __restrict__ h,
            const float* __restrict__ h0, float* __restrict__ sup, int n) {
    int node = (blockIdx.x << 2) + (threadIdx.x >> 6);
    if (node >= n) return;
    int lane = threadIdx.x & 63;
    const float2* h2  = (const float2*)h;
    const float2* h02 = (const float2*)h0;
    float di = dinv[node];
    float2 v  = h2[(size_t)node * 64 + lane];
    float2 a0 = h02[(size_t)node * 64 + lane];
    float ws = 0.9f * di * di;
    float ax = ws * v.x + 0.1f * a0.x;
    float ay = ws * v.y + 0.1f * a0.y;
    int e = offs[node], end = offs[node + 1];
    for (; e + 4 <= end; e += 4) {
        int2 c0 = csr[e + 0];
        int2 c1 = csr[e + 1];
        int2 c2 = csr[e + 2];
        int2 c3 = csr[e + 3];
        float2 v0 = h2[(size_t)c0.x * 64 + lane];
        float2 v1 = h2[(size_t)c1.x * 64 + lane];
        float2 v2 = h2[(size_t)c2.x * 64 + lane];
        float2 v3 = h2[(size_t)c3.x * 64 + lane];
        float w0 = __int_as_float(c0.y), w1 = __int_as_float(c1.y);
        float w2 = __int_as_float(c2.y), w3 = __int_as_float(c3.y);
        ax += w0 * v0.x; ay += w0 * v0.y;
        ax += w1 * v1.x; ay += w1 * v1.y;
        ax += w2 * v2.x; ay += w2 * v2.y;
        ax += w3 * v3.x; ay += w3 * v3.y;
    }
    for (; e < end; ++e) {
        int2 c = csr[e];
        float w = __int_as_float(c.y);
        float2 hv = h2[(size_t)c.x * 64 + lane];
        ax += w * hv.x; ay += w * hv.y;
    }
    float2 o; o.x = ax; o.y = ay;
    ((float2*)sup)[(size_t)node * 64 + lane] = o;
}

// ---------------- 128x128 fp32 GEMM, fused residual+relu ----------------
// out[r][c] = relu( beta*(in@W)[r][c] + resid*in[r][c] + bias[c] )
// 64-row tiles, 8x4 micro-tile per thread: 32 FMA per 3 ds_read_b128.

template<bool RELU, bool DUAL>
__global__ __launch_bounds__(256)
void gemm128(const float* __restrict__ in, const float* __restrict__ W,
             const float* __restrict__ bias, float beta, float resid,
             float* __restrict__ out, float* __restrict__ out2, int M) {
    __shared__ float Ws[32 * 128];   // K-panel of W (16 KB)
    __shared__ float xT[128 * 64];   // x tile, transposed [k][r] (32 KB)
    const int tid  = threadIdx.x;
    const int row0 = blockIdx.x * 64;

    // load x tile transposed: 64 rows x 32 float4
    {
        const float4* in4 = (const float4*)in;
        for (int i = tid; i < 2048; i += 256) {
            int r = i >> 5, c4 = i & 31;
            int gr = row0 + r;
            float4 v = make_float4(0.f, 0.f, 0.f, 0.f);
            if (gr < M) v = in4[(size_t)gr * 32 + c4];
            xT[(c4 * 4 + 0) * 64 + r] = v.x;
            xT[(c4 * 4 + 1) * 64 + r] = v.y;
            xT[(c4 * 4 + 2) * 64 + r] = v.z;
            xT[(c4 * 4 + 3) * 64 + r] = v.w;
        }
    }
    const int tr = tid >> 5;   // 0..7  -> rows tr*8..tr*8+7
    const int tc = tid & 31;   // 0..31 -> cols tc*4..tc*4+3
    float acc[8][4];
    #pragma unroll
    for (int i = 0; i < 8; ++i)
        #pragma unroll
        for (int j = 0; j < 4; ++j) acc[i][j] = 0.f;

    for (int kp = 0; kp < 4; ++kp) {
        __syncthreads();
        const float4* Wp = (const float4*)(W + kp * 32 * 128);
        for (int i = tid; i < 1024; i += 256)          // 32x128 = 1024 float4
            ((float4*)Ws)[i] = Wp[i];
        __syncthreads();
        #pragma unroll 8
        for (int k2 = 0; k2 < 32; ++k2) {
            int k = kp * 32 + k2;
            float4 a0 = *(const float4*)&xT[k * 64 + tr * 8];
            float4 a1 = *(const float4*)&xT[k * 64 + tr * 8 + 4];
            float4 b  = *(const float4*)&Ws[k2 * 128 + tc * 4];
            acc[0][0] += a0.x * b.x; acc[0][1] += a0.x * b.y; acc[0][2] += a0.x * b.z; acc[0][3] += a0.x * b.w;
            acc[1][0] += a0.y * b.x; acc[1][1] += a0.y * b.y; acc[1][2] += a0.y * b.z; acc[1][3] += a0.y * b.w;
            acc[2][0] += a0.z * b.x; acc[2][1] += a0.z * b.y; acc[2][2] += a0.z * b.z; acc[2][3] += a0.z * b.w;
            acc[3][0] += a0.w * b.x; acc[3][1] += a0.w * b.y; acc[3][2] += a0.w * b.z; acc[3][3] += a0.w * b.w;
            acc[4][0] += a1.x * b.x; acc[4][1] += a1.x * b.y; acc[4][2] += a1.x * b.z; acc[4][3] += a1.x * b.w;
            acc[5][0] += a1.y * b.x; acc[5][1] += a1.y * b.y; acc[5][2] += a1.y * b.z; acc[5][3] += a1.y * b.w;
            acc[6][0] += a1.z * b.x; acc[6][1] += a1.z * b.y; acc[6][2] += a1.z * b.z; acc[6][3] += a1.z * b.w;
            acc[7][0] += a1.w * b.x; acc[7][1] += a1.w * b.y; acc[7][2] += a1.w * b.z; acc[7][3] += a1.w * b.w;
        }
    }

    float bb[4] = {0.f, 0.f, 0.f, 0.f};
    if (bias) {
        #pragma unroll
        for (int j = 0; j < 4; ++j) bb[j] = bias[tc * 4 + j];
    }
    #pragma unroll
    for (int i = 0; i < 8; ++i) {
        int rl = tr * 8 + i;
        int r  = row0 + rl;
        if (r < M) {
            // residual re-read from global (coalesced, L2-hot) — avoids the
            // 32-way bank-conflict column read of xT.
            float4 x = *(const float4*)&in[(size_t)r * 128 + tc * 4];
            float s0 = beta * acc[i][0] + resid * x.x + bb[0];
            float s1 = beta * acc[i][1] + resid * x.y + bb[1];
            float s2 = beta * acc[i][2] + resid * x.z + bb[2];
            float s3 = beta * acc[i][3] + resid * x.w + bb[3];
            if (RELU) {
                s0 = fmaxf(s0, 0.f); s1 = fmaxf(s1, 0.f);
                s2 = fmaxf(s2, 0.f); s3 = fmaxf(s3, 0.f);
            }
            float4 o; o.x = s0; o.y = s1; o.z = s2; o.w = s3;
            *(float4*)&out[(size_t)r * 128 + tc * 4] = o;
            if (DUAL) *(float4*)&out2[(size_t)r * 128 + tc * 4] = o;
        }
    }
}

// ---------------- output GEMM: [M,128] @ [128,40] + b ----------------

__global__ __launch_bounds__(320)
void k_out(const float* __restrict__ h, const float* __restrict__ W,
           const float* __restrict__ b, float* __restrict__ out, int M, int C) {
    __shared__ float Ws[128 * 41];   // padded: bank-conflict-free scalar reads
    __shared__ float xs[32 * 132];   // padded rows, 16B-aligned float4 reads
    const int tid  = threadIdx.x;    // 320
    const int row0 = blockIdx.x * 32;

    for (int i = tid; i < 128 * 40; i += 320) {
        int k = i / 40, c = i % 40;
        Ws[k * 41 + c] = W[i];
    }
    {
        const float4* h4 = (const float4*)h;
        for (int i = tid; i < 1024; i += 320) {   // 32 rows x 32 float4
            int r = i >> 5, c4 = i & 31;
            int gr = row0 + r;
            float4 v = make_float4(0.f, 0.f, 0.f, 0.f);
            if (gr < M) v = h4[(size_t)gr * 32 + c4];
            *(float4*)&xs[r * 132 + c4 * 4] = v;
        }
    }
    __syncthreads();

    const int c  = tid % 40;
    const int rg = tid / 40;          // 0..7 -> rows rg*4..rg*4+3
    float acc[4] = {0.f, 0.f, 0.f, 0.f};
    #pragma unroll 4
    for (int k4 = 0; k4 < 32; ++k4) {
        float w0 = Ws[(k4 * 4 + 0) * 41 + c];
        float w1 = Ws[(k4 * 4 + 1) * 41 + c];
        float w2 = Ws[(k4 * 4 + 2) * 41 + c];
        float w3 = Ws[(k4 * 4 + 3) * 41 + c];
        #pragma unroll
        for (int i = 0; i < 4; ++i) {
            float4 x = *(const float4*)&xs[(rg * 4 + i) * 132 + k4 * 4];
            acc[i] += x.x * w0 + x.y * w1 + x.z * w2 + x.w * w3;
        }
    }
    float bb = b[c];
    #pragma unroll
    for (int i = 0; i < 4; ++i) {
        int r = row0 + rg * 4 + i;
        if (r < M) out[(size_t)r * C + c] = acc[i] + bb;
    }
}

// ---------------- host ----------------

extern "C" void kernel_launch(void* const* d_in, const int* in_sizes, int n_in,
                              void* d_out, int out_size, void* d_ws, size_t ws_size,
                              hipStream_t stream) {
    const float* x        = (const float*)d_in[0];
    const int*   ei       = (const int*)d_in[1];
    const float* W_in     = (const float*)d_in[2];
    const float* b_in     = (const float*)d_in[3];
    const float* W_layers = (const float*)d_in[4];
    const float* W_out    = (const float*)d_in[5];
    const float* b_out    = (const float*)d_in[6];
    float* out = (float*)d_out;

    const int H = 128;
    const int N = in_sizes[0] / H;             // 50000
    const int E = in_sizes[1] / 2;             // 800000
    const int L = in_sizes[4] / (H * H);       // 4
    const int C = in_sizes[5] / H;             // 40

    // workspace carve (256B aligned)
    char* p = (char*)d_ws;
    auto alloc = [&](size_t bytes) {
        char* r = p;
        p += (bytes + 255) & ~(size_t)255;
        return r;
    };
    int*   cnt   = (int*)alloc((size_t)N * 4);
    int*   offs  = (int*)alloc((size_t)(N + 1) * 4);
    int*   parts = (int*)alloc(256 * 4);
    int2*  csr   = (int2*)alloc((size_t)E * 8);
    float* dinv  = (float*)alloc((size_t)N * 4);
    float* h0    = (float*)alloc((size_t)N * H * 4);
    float* hA    = (float*)alloc((size_t)N * H * 4);
    float* hB    = (float*)alloc((size_t)N * H * 4);
    (void)ws_size;

    const int* ei0 = ei;        // destinations (row)
    const int* ei1 = ei + E;    // sources (col)

    const int nblkN = (N + 255) / 256;
    const int nblkE = (E + 255) / 256;

    hipMemsetAsync(cnt, 0, (size_t)N * 4, stream);
    k_count<<<nblkE, 256, 0, stream>>>(ei0, cnt, E);
    k_dinv<<<nblkN, 256, 0, stream>>>(cnt, dinv, N);
    k_scan_part<<<nblkN, 256, 0, stream>>>(cnt, offs, parts, N);
    k_scan_tops<<<1, 256, 0, stream>>>(parts, nblkN);
    k_scan_add<<<nblkN, 256, 0, stream>>>(offs, parts, N, E);
    hipMemsetAsync(cnt, 0, (size_t)N * 4, stream);
    k_scatter<<<nblkE, 256, 0, stream>>>(ei0, ei1, offs, cnt, dinv, csr, E);

    const int gblk = (N + 63) / 64;

    // input linear + relu -> hA, copy -> h0
    gemm128<true, true><<<gblk, 256, 0, stream>>>(x, W_in, b_in, 1.0f, 0.0f, hA, h0, N);

    for (int l = 0; l < L; ++l) {
        float beta = logf(0.5f / (float)(l + 1) + 1.0f);
        k_spmm<<<(N + 3) / 4, 256, 0, stream>>>(offs, csr, dinv, hA, h0, hB, N);
        gemm128<true, false><<<gblk, 256, 0, stream>>>(
            hB, W_layers + (size_t)l * H * H, nullptr, beta, 1.0f - beta, hA, nullptr, N);
    }

    k_out<<<(N + 31) / 32, 320, 0, stream>>>(hA, W_out, b_out, out, N, C);
}